// Round 2
// baseline (909.949 us; speedup 1.0000x reference)
//
#include <hip/hip_runtime.h>

// ---------------------------------------------------------------------------
// ChemistryAwareDecoder on MI355X (gfx950)
// N=100000 nodes, E=200000 edges, SD=128, CD=768
// R8: R6/R7 both sat at 389us with all pipes <25% and occupancy pinned at
// 33% -- register-capped at 3 waves/SIMD (76 arch VGPR + ~56 AGPR acc).
// Pipeline depth was neutral (R7) => latency-bound from occupancy.
// This round: 512 threads / 8 waves per 32-edge block; each wave owns ONE
// M-tile (mt=w>>2) x 5 N-tiles (g=w&3). Accs 40->20 f32/wave, A-frags 4->2,
// staging 8B/thread (f32x2). Target: 4-6 waves/SIMD instead of 3.
// ---------------------------------------------------------------------------

typedef float    f32x4 __attribute__((ext_vector_type(4)));
typedef float    f32x2 __attribute__((ext_vector_type(2)));
typedef _Float16 f16x8 __attribute__((ext_vector_type(8)));
typedef _Float16 f16x2 __attribute__((ext_vector_type(2)));

#define E_EDGES 200000
#define KSTEPS  28                    // 896 / 32
#define NOUT    384                   // 64 + 192 + 128 fused outputs
#define PTOT    (KSTEPS * NOUT * 32)  // 344064 weight elements
#define PANEL   (NOUT * 32)           // 12288 halfs per k-step panel

// workspace layout (bytes)
#define WS_WH    0
#define WS_B1    688128
#define WS_W2    (688128 + 1536)
#define WS_CONST (688128 + 3072)

// ---------------------------------------------------------------------------
// Prep: fused block-diagonal weight panels in f16 (RNE), fused bias/layer-2
// vectors, softmax consts, edge-dtype detection.
// Panel: wh[p][n][kk], p = k/32, n = 0..383, kk = k%32.
// Wbig[k][n]: n<64: sw1 (k<128) | n<256: cw1 (k>=128) | n>=256: mw1 (all k)
// ---------------------------------------------------------------------------
__global__ __launch_bounds__(256) void prep_kernel(
    const float* __restrict__ sw1, const float* __restrict__ sb1,
    const float* __restrict__ sw2, const float* __restrict__ sb2,
    const float* __restrict__ cw1, const float* __restrict__ cb1,
    const float* __restrict__ cw2, const float* __restrict__ cb2,
    const float* __restrict__ mw1, const float* __restrict__ mb1,
    const float* __restrict__ mw2, const float* __restrict__ mb2,
    const float* __restrict__ pw,  const int* __restrict__ edge_i32,
    _Float16* __restrict__ wh,
    float* __restrict__ b1cat, float* __restrict__ w2cat,
    float* __restrict__ consts)
{
  const int idx = blockIdx.x * 256 + threadIdx.x;
  if (idx < PTOT) {
    const int p  = idx / PANEL;
    const int r  = idx % PANEL;
    const int n  = r >> 5;
    const int kk = r & 31;
    const int k  = p * 32 + kk;
    float v;
    if (n < 64)       v = (k < 128)  ? sw1[k * 64 + n] : 0.0f;
    else if (n < 256) v = (k >= 128) ? cw1[(size_t)(k - 128) * 192 + (n - 64)] : 0.0f;
    else              v = mw1[(size_t)k * 128 + (n - 256)];
    wh[idx] = (_Float16)v;  // RNE
  } else if (idx < PTOT + NOUT) {
    const int j = idx - PTOT;
    float b, w;
    if (j < 64)       { b = sb1[j];       w = sw2[j]; }
    else if (j < 256) { b = cb1[j - 64];  w = cw2[j - 64]; }
    else              { b = mb1[j - 256]; w = mw2[j - 256]; }
    b1cat[j] = b;
    w2cat[j] = w;
  } else if (idx == PTOT + NOUT) {
    const float p0 = pw[0], p1 = pw[1], p2 = pw[2];
    const float mx = fmaxf(p0, fmaxf(p1, p2));
    const float e0 = __expf(p0 - mx), e1 = __expf(p1 - mx), e2 = __expf(p2 - mx);
    const float inv = 1.0f / (e0 + e1 + e2);
    const float w0 = e0 * inv, w1 = e1 * inv, w2v = e2 * inv;
    consts[0] = w0; consts[1] = w1; consts[2] = w2v;
    consts[3] = w0 * sb2[0] + w1 * cb2[0] + w2v * mb2[0];  // valid-path bias
    consts[4] = sb2[0];                                    // invalid-path bias
    unsigned o = 0;
    for (int i = 0; i < 64; ++i) o |= (unsigned)edge_i32[2 * i + 1];
    consts[5] = (o == 0u) ? 1.0f : 0.0f;  // 1 => int64 edge layout
  }
}

// f16x2 compensated: (ah+al)*bh = a*bh; error ~ 2^-12 |ab| per term
#define FMA2(ACC, AH, AL, B)                                              \
  ACC = __builtin_amdgcn_mfma_f32_16x16x32_f16(AH, B, ACC, 0, 0, 0);      \
  ACC = __builtin_amdgcn_mfma_f32_16x16x32_f16(AL, B, ACC, 0, 0, 0);

// ---------------------------------------------------------------------------
// Main: grid = E/32 = 6250 blocks of 512 threads (8 waves). Block owns edges
// [32b, 32b+32): M-tile0 rows 0-15, tile1 rows 16-31. N-tiles: 0-3
// structural (k<128), 4-15 chemical (k>=128), 16-23 combined (all k).
// Wave w: mt = w>>2 (its single M-tile), g = w&3 (its N-tile group):
//   phase A: S{g}, C{16+2g,17+2g}; phase B: H{4+3g..6+3g}, C{16+2g,17+2g}.
// Staging: thread tid loads 8B of edge (tid>>4)'s src and dst rows at
// k-chunk (tid&15)*2 (16 consecutive lanes cover one 128B row segment);
// products split f16 hi/lo into a 4-deep LDS ring. Pipeline per step s:
//   consume buf[s&3] -> MFMAs -> stage buf[(s+2)&3] -> issue gather s+4.
// Barrier after every second step.
// ---------------------------------------------------------------------------
__global__ __launch_bounds__(512, 5) void decoder_main(
    const float* __restrict__ z, const float* __restrict__ chem,
    const int* __restrict__ edge, const int* __restrict__ mask,
    const _Float16* __restrict__ wh,
    const float* __restrict__ b1cat, const float* __restrict__ w2cat,
    const float* __restrict__ consts, float* __restrict__ out)
{
  __shared__ _Float16 Ash[2][4][32][40];  // [hi/lo][ring buf][row][kk], 20.5 KB
  __shared__ int   srcL[32];
  __shared__ int   dstL[32];
  __shared__ float validL[32];
  __shared__ float scoreW[8][32];

  const int tid  = threadIdx.x;
  const int lane = tid & 63;
  const int wv   = tid >> 6;          // 0..7
  const int g    = wv & 3;            // N-tile group
  const int mrow = (wv >> 2) << 4;    // M-tile base row (0 or 16)
  const int li   = lane & 15;
  const int q    = lane >> 4;
  const int q8   = q << 3;
  const int base = blockIdx.x * 32;   // E = 6250*32 exactly

  if (tid < 32) {
    const int e = base + tid;
    int s_, d_;
    if (consts[5] > 0.5f) { s_ = edge[4 * e]; d_ = edge[4 * e + 2]; }  // int64
    else                  { s_ = edge[2 * e]; d_ = edge[2 * e + 1]; }  // int32
    srcL[tid] = s_;
    dstL[tid] = d_;
    validL[tid] = (mask[s_] != 0 && mask[d_] != 0) ? 1.0f : 0.0f;
  }
  __syncthreads();

  // cooperative staging slots: edge row m, k-chunk kc (coalesced: 16
  // consecutive lanes cover one 128B row segment, 8B each)
  const int m  = tid >> 4;            // 0..31
  const int kc = (tid & 15) << 1;     // float offset 0,2,..,30
  const float* zs = z    + (size_t)srcL[m] * 128 + kc;
  const float* zd = z    + (size_t)dstL[m] * 128 + kc;
  const float* cs = chem + (size_t)srcL[m] * 768 + kc;
  const float* cd = chem + (size_t)dstL[m] * 768 + kc;

  const int loff = li * 32 + q8;      // lane offset within a B panel
  const int tS  = g;                  // structural, phase A
  const int tH0 = 4 + 3 * g;          // chemical, phase B
  const int tC0 = 16 + 2 * g;         // combined, both phases

  // gather for k-step t (t<4: z, else chem) - prologue only
#define GLOAD(T, GA, GB)                                    \
  if ((T) < 4) {                                            \
    GA = *(const f32x2*)(zs + (T) * 32);                    \
    GB = *(const f32x2*)(zd + (T) * 32);                    \
  } else {                                                  \
    GA = *(const f32x2*)(cs + ((T) - 4) * 32);              \
    GB = *(const f32x2*)(cd + ((T) - 4) * 32);              \
  }

  // issue gather for step S+4 (always chem side since S >= 0 -> target >= 4)
#define ISSUE(S, GA, GB)                                    \
  { GA = *(const f32x2*)(cs + (size_t)(S) * 32);            \
    GB = *(const f32x2*)(cd + (size_t)(S) * 32); }

  // product -> f16 hi/lo -> LDS ring buffer BUF (2 floats -> 2x 4B stores)
#define STAGE(BUF, PA, PB)                                  \
  {                                                         \
    f16x2 h_, l_;                                           \
    _Pragma("unroll")                                       \
    for (int j = 0; j < 2; ++j) {                           \
      const float p_ = (PA)[j] * (PB)[j];                   \
      const _Float16 hh = (_Float16)p_;                     \
      h_[j] = hh;                                           \
      l_[j] = (_Float16)(p_ - (float)hh);                   \
    }                                                       \
    *(f16x2*)&Ash[0][BUF][m][kc] = h_;                      \
    *(f16x2*)&Ash[1][BUF][m][kc] = l_;                      \
  }

  // this wave's single M-tile A fragments
#define AFRAGS(BC, AH, AL)                                  \
  AH = *(const f16x8*)&Ash[0][BC][mrow + li][q8];           \
  AL = *(const f16x8*)&Ash[1][BC][mrow + li][q8];

  const float w0c = consts[0], w1c = consts[1], w2c = consts[2];

  float part[4];
#pragma unroll
  for (int r = 0; r < 4; ++r) part[r] = 0.0f;

  // retire one tile's acc into part with path weighting.
  // C/D layout: col = ti*16+li, row = mrow + q*4+r.
#define RETIRE(ACC, TI, WVALID, WINVALID)                                  \
  {                                                                        \
    const int col = (TI) * 16 + li;                                        \
    const float b1 = b1cat[col];                                           \
    const float w2 = w2cat[col];                                           \
    _Pragma("unroll")                                                      \
    for (int r = 0; r < 4; ++r) {                                          \
      const float vld = validL[mrow + q * 4 + r];                          \
      const float a = (WINVALID) + vld * ((WVALID) - (WINVALID));          \
      part[r] += a * fmaxf((ACC)[r] + b1, 0.0f) * w2;                      \
    }                                                                      \
  }

  // ---- pipeline prologue: issue G0..G3, stage buf0/buf1 ------------------
  // Register sets: gx carries G(t) for even t, gy for odd t.
  f32x2 g0a, g0b, g1a, g1b, gxa, gxb, gya, gyb;
  GLOAD(0, g0a, g0b)
  GLOAD(1, g1a, g1b)
  GLOAD(2, gxa, gxb)
  GLOAD(3, gya, gyb)
  STAGE(0, g0a, g0b)
  STAGE(1, g1a, g1b)
  __syncthreads();

  // ---------------- phase A: s = 0..3 (S + C tiles) ----------------------
  f32x4 accS, accC[2];
  accS = (f32x4){0.f, 0.f, 0.f, 0.f};
  accC[0] = (f32x4){0.f, 0.f, 0.f, 0.f};
  accC[1] = (f32x4){0.f, 0.f, 0.f, 0.f};

#define STEP_A(S, GA, GB)                                           \
  {                                                                 \
    const int bc = (S) & 3;                                         \
    f16x8 ah, al;                                                   \
    AFRAGS(bc, ah, al)                                              \
    const _Float16* bu = wh + (size_t)(S) * PANEL + loff;           \
    const f16x8 bS  = *(const f16x8*)(bu + tS * 512);               \
    const f16x8 bC0 = *(const f16x8*)(bu + tC0 * 512);              \
    const f16x8 bC1 = *(const f16x8*)(bu + tC0 * 512 + 512);        \
    FMA2(accS,    ah, al, bS)                                       \
    FMA2(accC[0], ah, al, bC0)                                      \
    FMA2(accC[1], ah, al, bC1)                                      \
    STAGE((bc + 2) & 3, GA, GB)                                     \
    ISSUE((S), GA, GB)                                              \
  }

  STEP_A(0, gxa, gxb)
  STEP_A(1, gya, gyb)
  __syncthreads();
  STEP_A(2, gxa, gxb)
  STEP_A(3, gya, gyb)
  __syncthreads();

  // retire structural (k-range done): valid ? w0 : 1
  RETIRE(accS, tS, w0c, 1.0f)

  // ---------------- phase B: s = 4..27 (H + C tiles) ----------------------
  f32x4 accH[3];
#pragma unroll
  for (int t = 0; t < 3; ++t) accH[t] = (f32x4){0.f, 0.f, 0.f, 0.f};

#define STEP_B(S, GA, GB, DO_STAGE, DO_ISSUE)                       \
  {                                                                 \
    const int bc = (S) & 3;                                         \
    f16x8 ah, al;                                                   \
    AFRAGS(bc, ah, al)                                              \
    const _Float16* bu = wh + (size_t)(S) * PANEL + loff;           \
    const f16x8 bH0 = *(const f16x8*)(bu + tH0 * 512);              \
    const f16x8 bH1 = *(const f16x8*)(bu + tH0 * 512 + 512);        \
    const f16x8 bH2 = *(const f16x8*)(bu + tH0 * 512 + 1024);       \
    const f16x8 bC0 = *(const f16x8*)(bu + tC0 * 512);              \
    const f16x8 bC1 = *(const f16x8*)(bu + tC0 * 512 + 512);        \
    FMA2(accH[0], ah, al, bH0)                                      \
    FMA2(accH[1], ah, al, bH1)                                      \
    FMA2(accH[2], ah, al, bH2)                                      \
    FMA2(accC[0], ah, al, bC0)                                      \
    FMA2(accC[1], ah, al, bC1)                                      \
    if (DO_STAGE) STAGE((bc + 2) & 3, GA, GB)                       \
    if (DO_ISSUE) ISSUE((S), GA, GB)                                \
  }

  // main supersteps: steps 4..23, stage s+2, issue s+4, barrier per 2 steps
  for (int u = 2; u < 12; ++u) {
    STEP_B(2 * u,     gxa, gxb, true, true)
    STEP_B(2 * u + 1, gya, gyb, true, true)
    __syncthreads();
  }
  // superstep 12: steps 24,25 - stage 26,27; nothing left to issue
  STEP_B(24, gxa, gxb, true,  false)
  STEP_B(25, gya, gyb, true,  false)
  __syncthreads();
  // superstep 13: steps 26,27 - drain
  STEP_B(26, gxa, gxb, false, false)
  STEP_B(27, gya, gyb, false, false)

  // retire chemical (valid ? w1 : 0) and combined (valid ? w2 : 0)
#pragma unroll
  for (int t = 0; t < 3; ++t) {
    RETIRE(accH[t], tH0 + t, w1c, 0.0f)
  }
#pragma unroll
  for (int t = 0; t < 2; ++t) {
    RETIRE(accC[t], tC0 + t, w2c, 0.0f)
  }

  // ---------------- reduce 16 cols per quad (uniform flow) ---------------
#pragma unroll
  for (int r = 0; r < 4; ++r) {
    float vv = part[r];
    vv += __shfl_xor(vv, 1);
    vv += __shfl_xor(vv, 2);
    vv += __shfl_xor(vv, 4);
    vv += __shfl_xor(vv, 8);
    part[r] = vv;   // full sum now in every lane of the quad
  }
  // per-wave partials to LDS (plain stores; no cross-lane in divergent flow)
  if (li == 0) {
#pragma unroll
    for (int r = 0; r < 4; ++r)
      scoreW[wv][mrow + q * 4 + r] = part[r];
  }
  __syncthreads();

  // final cross-wave sum + bias select: row t<16 came from waves 0-3 (mt=0),
  // t>=16 from waves 4-7 (mt=1)
  if (tid < 32) {
    const int w0 = (tid >> 4) << 2;
    const float s4 = scoreW[w0][tid] + scoreW[w0 + 1][tid] +
                     scoreW[w0 + 2][tid] + scoreW[w0 + 3][tid];
    const float c3 = consts[3], c4 = consts[4];
    out[base + tid] = s4 + c4 + validL[tid] * (c3 - c4);
  }
}

// ---------------------------------------------------------------------------
extern "C" void kernel_launch(void* const* d_in, const int* in_sizes, int n_in,
                              void* d_out, int out_size, void* d_ws, size_t ws_size,
                              hipStream_t stream)
{
  const float* z    = (const float*)d_in[0];
  const float* chem = (const float*)d_in[1];
  const int*   edge = (const int*)d_in[2];
  const int*   mask = (const int*)d_in[3];
  const float* sw1  = (const float*)d_in[4];
  const float* sb1  = (const float*)d_in[5];
  const float* sw2  = (const float*)d_in[6];
  const float* sb2  = (const float*)d_in[7];
  const float* cw1  = (const float*)d_in[8];
  const float* cb1  = (const float*)d_in[9];
  const float* cw2  = (const float*)d_in[10];
  const float* cb2  = (const float*)d_in[11];
  const float* mw1  = (const float*)d_in[12];
  const float* mb1  = (const float*)d_in[13];
  const float* mw2  = (const float*)d_in[14];
  const float* mb2  = (const float*)d_in[15];
  const float* pw   = (const float*)d_in[16];

  char* ws = (char*)d_ws;
  _Float16* wh  = (_Float16*)(ws + WS_WH);
  float* b1cat  = (float*)(ws + WS_B1);
  float* w2cat  = (float*)(ws + WS_W2);
  float* consts = (float*)(ws + WS_CONST);

  const int prep_tasks  = PTOT + NOUT + 64;
  const int prep_blocks = (prep_tasks + 255) / 256;
  prep_kernel<<<prep_blocks, 256, 0, stream>>>(
      sw1, sb1, sw2, sb2, cw1, cb1, cw2, cb2, mw1, mb1, mw2, mb2, pw, edge,
      wh, b1cat, w2cat, consts);

  decoder_main<<<E_EDGES / 32, 512, 0, stream>>>(
      z, chem, edge, mask, wh, b1cat, w2cat, consts, (float*)d_out);
}

// Round 3
// 821.573 us; speedup vs baseline: 1.1076x; 1.1076x over previous
//
#include <hip/hip_runtime.h>

// ---------------------------------------------------------------------------
// ChemistryAwareDecoder on MI355X (gfx950)
// N=100000 nodes, E=200000 edges, SD=128, CD=768
// R9: R8 falsified occupancy theory (45% occ, 592us, all pipes DOWN) and
// proved the limiter is L1/TCP line servicing: duration tracks vmem line
// touches (B-panel touches doubled -> +52%). Per 32-edge block: gather 3.6k
// lines (irreducible) + B-panel 4.5k lines (same panel for every block!).
// This round: keep R6's per-wave shape exactly (2 M-tiles x 5 N-tiles, 40
// acc regs, same 389us-proven schedule) but 768 threads / 12 waves / 96
// edges per block = 3 M-groups x 4 N-groups. Same-g waves of the 3 M-groups
// share each B line within a barrier window -> per-edge B-line traffic /3.
// ---------------------------------------------------------------------------

typedef float    f32x4 __attribute__((ext_vector_type(4)));
typedef _Float16 f16x8 __attribute__((ext_vector_type(8)));
typedef _Float16 f16x4 __attribute__((ext_vector_type(4)));

#define E_EDGES 200000
#define EPB     96                    // edges per block
#define NBLK    ((E_EDGES + EPB - 1) / EPB)   // 2084
#define KSTEPS  28                    // 896 / 32
#define NOUT    384                   // 64 + 192 + 128 fused outputs
#define PTOT    (KSTEPS * NOUT * 32)  // 344064 weight elements
#define PANEL   (NOUT * 32)           // 12288 halfs per k-step panel

// workspace layout (bytes)
#define WS_WH    0
#define WS_B1    688128
#define WS_W2    (688128 + 1536)
#define WS_CONST (688128 + 3072)

// ---------------------------------------------------------------------------
// Prep: fused block-diagonal weight panels in f16 (RNE), fused bias/layer-2
// vectors, softmax consts, edge-dtype detection.
// Panel: wh[p][n][kk], p = k/32, n = 0..383, kk = k%32.
// Wbig[k][n]: n<64: sw1 (k<128) | n<256: cw1 (k>=128) | n>=256: mw1 (all k)
// ---------------------------------------------------------------------------
__global__ __launch_bounds__(256) void prep_kernel(
    const float* __restrict__ sw1, const float* __restrict__ sb1,
    const float* __restrict__ sw2, const float* __restrict__ sb2,
    const float* __restrict__ cw1, const float* __restrict__ cb1,
    const float* __restrict__ cw2, const float* __restrict__ cb2,
    const float* __restrict__ mw1, const float* __restrict__ mb1,
    const float* __restrict__ mw2, const float* __restrict__ mb2,
    const float* __restrict__ pw,  const int* __restrict__ edge_i32,
    _Float16* __restrict__ wh,
    float* __restrict__ b1cat, float* __restrict__ w2cat,
    float* __restrict__ consts)
{
  const int idx = blockIdx.x * 256 + threadIdx.x;
  if (idx < PTOT) {
    const int p  = idx / PANEL;
    const int r  = idx % PANEL;
    const int n  = r >> 5;
    const int kk = r & 31;
    const int k  = p * 32 + kk;
    float v;
    if (n < 64)       v = (k < 128)  ? sw1[k * 64 + n] : 0.0f;
    else if (n < 256) v = (k >= 128) ? cw1[(size_t)(k - 128) * 192 + (n - 64)] : 0.0f;
    else              v = mw1[(size_t)k * 128 + (n - 256)];
    wh[idx] = (_Float16)v;  // RNE
  } else if (idx < PTOT + NOUT) {
    const int j = idx - PTOT;
    float b, w;
    if (j < 64)       { b = sb1[j];       w = sw2[j]; }
    else if (j < 256) { b = cb1[j - 64];  w = cw2[j - 64]; }
    else              { b = mb1[j - 256]; w = mw2[j - 256]; }
    b1cat[j] = b;
    w2cat[j] = w;
  } else if (idx == PTOT + NOUT) {
    const float p0 = pw[0], p1 = pw[1], p2 = pw[2];
    const float mx = fmaxf(p0, fmaxf(p1, p2));
    const float e0 = __expf(p0 - mx), e1 = __expf(p1 - mx), e2 = __expf(p2 - mx);
    const float inv = 1.0f / (e0 + e1 + e2);
    const float w0 = e0 * inv, w1 = e1 * inv, w2v = e2 * inv;
    consts[0] = w0; consts[1] = w1; consts[2] = w2v;
    consts[3] = w0 * sb2[0] + w1 * cb2[0] + w2v * mb2[0];  // valid-path bias
    consts[4] = sb2[0];                                    // invalid-path bias
    unsigned o = 0;
    for (int i = 0; i < 64; ++i) o |= (unsigned)edge_i32[2 * i + 1];
    consts[5] = (o == 0u) ? 1.0f : 0.0f;  // 1 => int64 edge layout
  }
}

// f16x2 compensated: (ah+al)*bh = a*bh; error ~ 2^-12 |ab| per term
#define FMA2(ACC, AH, AL, B)                                              \
  ACC = __builtin_amdgcn_mfma_f32_16x16x32_f16(AH, B, ACC, 0, 0, 0);      \
  ACC = __builtin_amdgcn_mfma_f32_16x16x32_f16(AL, B, ACC, 0, 0, 0);

// ---------------------------------------------------------------------------
// Main: grid = 2084 blocks of 768 threads (12 waves). Block owns edges
// [96b, 96b+96): M-group mg = wv>>2 covers rows [32mg, 32mg+32) as 2 M-tiles
// of 16. N-tiles: 0-3 structural (k<128), 4-15 chemical (k>=128), 16-23
// combined (all k). Wave (mg, g=wv&3) owns: S{g} (phase A), H{4+3g..6+3g}
// (phase B), C{16+2g,17+2g} (both) for its 32 rows. The 3 same-g waves read
// identical B fragments within one barrier window -> L1 temporal hits;
// per-edge B-line traffic is 1/3 of the 32-edge-block version.
// Staging is block-cooperative & coalesced: thread tid loads 16B of edge
// (tid>>3)'s src and dst rows at k-chunk (tid&7)*4; products split f16 hi/lo
// into double-buffered LDS. 2-step-deep gather prefetch. 1 barrier/step.
// ---------------------------------------------------------------------------
__global__ __launch_bounds__(768, 3) void decoder_main(
    const float* __restrict__ z, const float* __restrict__ chem,
    const int* __restrict__ edge, const int* __restrict__ mask,
    const _Float16* __restrict__ wh,
    const float* __restrict__ b1cat, const float* __restrict__ w2cat,
    const float* __restrict__ consts, float* __restrict__ out)
{
  __shared__ _Float16 Ah[2][96][40];  // stride 40 halfs: 16B-aligned, 2-way banks
  __shared__ _Float16 Al[2][96][40];
  __shared__ int   srcL[96];
  __shared__ int   dstL[96];
  __shared__ float validL[96];
  __shared__ float scoreW[12][32];

  const int tid  = threadIdx.x;
  const int lane = tid & 63;
  const int wv   = tid >> 6;          // 0..11
  const int g    = wv & 3;            // N-tile group
  const int mrow = (wv >> 2) << 5;    // M-group base row: 0, 32, 64
  const int li   = lane & 15;
  const int q    = lane >> 4;
  const int base = blockIdx.x * EPB;

  if (tid < EPB) {
    const int e = base + tid;
    int s_ = 0, d_ = 0, ok = 0;
    if (e < E_EDGES) {
      if (consts[5] > 0.5f) { s_ = edge[4 * e]; d_ = edge[4 * e + 2]; }  // int64
      else                  { s_ = edge[2 * e]; d_ = edge[2 * e + 1]; }  // int32
      ok = 1;
    }
    srcL[tid] = s_;
    dstL[tid] = d_;
    validL[tid] = (ok && mask[s_] != 0 && mask[d_] != 0) ? 1.0f : 0.0f;
  }
  __syncthreads();

  // cooperative staging slots: edge row m, k-chunk kc (coalesced: 8
  // consecutive lanes cover one 128B row segment)
  const int m  = tid >> 3;            // 0..95
  const int kc = (tid & 7) << 2;
  const float* zs = z    + (size_t)srcL[m] * 128 + kc;
  const float* zd = z    + (size_t)dstL[m] * 128 + kc;
  const float* cs = chem + (size_t)srcL[m] * 768 + kc;
  const float* cd = chem + (size_t)dstL[m] * 768 + kc;

  // gather for k-step t (t<4: z, else chem)
#define GLOAD(T, A, B)                                      \
  if ((T) < 4) {                                            \
    A = *(const f32x4*)(zs + (T) * 32);                     \
    B = *(const f32x4*)(zd + (T) * 32);                     \
  } else {                                                  \
    A = *(const f32x4*)(cs + ((T) - 4) * 32);               \
    B = *(const f32x4*)(cd + ((T) - 4) * 32);               \
  }

  // product -> f16 hi/lo -> LDS (4 values, 8B to Ah + 8B to Al)
#define STAGE(BUF, PA, PB)                                  \
  {                                                         \
    f16x4 h_, l_;                                           \
    _Pragma("unroll")                                       \
    for (int j = 0; j < 4; ++j) {                           \
      const float p_ = (PA)[j] * (PB)[j];                   \
      const _Float16 hh = (_Float16)p_;                     \
      h_[j] = hh;                                           \
      l_[j] = (_Float16)(p_ - (float)hh);                   \
    }                                                       \
    *(f16x4*)&Ah[BUF][m][kc] = h_;                          \
    *(f16x4*)&Al[BUF][m][kc] = l_;                          \
  }

  // B fragment: tile ti at step s (proven panel indexing)
#define BFRAG(S, TI) \
  (*(const f16x8*)(wh + (size_t)(S) * PANEL + ((TI) * 16 + li) * 32 + q * 8))

  // A fragments for this wave's M-group (2 M-tiles) from LDS buffer
#define AFRAGS(BUF, A0H, A0L, A1H, A1L)                     \
  A0H = *(const f16x8*)&Ah[BUF][mrow + li][q * 8];          \
  A0L = *(const f16x8*)&Al[BUF][mrow + li][q * 8];          \
  A1H = *(const f16x8*)&Ah[BUF][mrow + 16 + li][q * 8];     \
  A1L = *(const f16x8*)&Al[BUF][mrow + 16 + li][q * 8];

  const float w0c = consts[0], w1c = consts[1], w2c = consts[2];

  float part[2][4];
#pragma unroll
  for (int mt = 0; mt < 2; ++mt)
#pragma unroll
    for (int r = 0; r < 4; ++r) part[mt][r] = 0.0f;

  // retire one tile's acc into part with path weighting.
  // C/D layout: col = ti*16+li, row = mrow + mt*16 + q*4+r.
#define RETIRE(ACC, TI, MT, WVALID, WINVALID)                              \
  {                                                                        \
    const int col = (TI) * 16 + li;                                        \
    const float b1 = b1cat[col];                                           \
    const float w2 = w2cat[col];                                           \
    _Pragma("unroll")                                                      \
    for (int r = 0; r < 4; ++r) {                                          \
      const float vld = validL[mrow + (MT) * 16 + q * 4 + r];              \
      const float a = (WINVALID) + vld * ((WVALID) - (WINVALID));          \
      part[MT][r] += a * fmaxf((ACC)[r] + b1, 0.0f) * w2;                  \
    }                                                                      \
  }

  // this wave's tile indices
  const int tS  = g;              // structural, phase A
  const int tH0 = 4 + 3 * g;      // chemical, phase B
  const int tC0 = 16 + 2 * g;     // combined, both phases

  // ---- pipeline prologue: stage s=0; prefetch s=1 --------------------
  {
    f32x4 a0, b0;
    GLOAD(0, a0, b0)
    STAGE(0, a0, b0)
  }
  f32x4 gca, gcb;   // gathers for step s+1 (consumed next STAGE)
  GLOAD(1, gca, gcb)
  __syncthreads();

  // ---------------- phase A: s = 0..3 (S + C tiles) ----------------------
  f32x4 accS[2], accC[2][2];
  accS[0] = (f32x4){0.f, 0.f, 0.f, 0.f};
  accS[1] = (f32x4){0.f, 0.f, 0.f, 0.f};
#pragma unroll
  for (int t = 0; t < 2; ++t) {
    accC[t][0] = (f32x4){0.f, 0.f, 0.f, 0.f};
    accC[t][1] = (f32x4){0.f, 0.f, 0.f, 0.f};
  }

#pragma unroll
  for (int s = 0; s < 4; ++s) {
    const int buf = s & 1;
    f16x8 a0h, a0l, a1h, a1l;
    AFRAGS(buf, a0h, a0l, a1h, a1l)

    const f16x8 bS  = BFRAG(s, tS);
    const f16x8 bC0 = BFRAG(s, tC0);
    const f16x8 bC1 = BFRAG(s, tC0 + 1);

    // prefetch s+2 (two full steps to land)
    f32x4 gna, gnb;
    GLOAD(s + 2, gna, gnb)

    FMA2(accS[0], a0h, a0l, bS)
    FMA2(accS[1], a1h, a1l, bS)
    FMA2(accC[0][0], a0h, a0l, bC0)
    FMA2(accC[0][1], a1h, a1l, bC0)
    FMA2(accC[1][0], a0h, a0l, bC1)
    FMA2(accC[1][1], a1h, a1l, bC1)

    STAGE(buf ^ 1, gca, gcb)   // stage s+1 from the older prefetch
    __syncthreads();
    gca = gna; gcb = gnb;
  }

  // retire structural (k-range done): valid ? w0 : 1
  RETIRE(accS[0], tS, 0, w0c, 1.0f)
  RETIRE(accS[1], tS, 1, w0c, 1.0f)

  // ---------------- phase B: s = 4..27 (H + C tiles) ----------------------
  f32x4 accH[3][2];
#pragma unroll
  for (int t = 0; t < 3; ++t) {
    accH[t][0] = (f32x4){0.f, 0.f, 0.f, 0.f};
    accH[t][1] = (f32x4){0.f, 0.f, 0.f, 0.f};
  }

  for (int s = 4; s < KSTEPS; ++s) {
    const int buf = s & 1;
    f16x8 a0h, a0l, a1h, a1l;
    AFRAGS(buf, a0h, a0l, a1h, a1l)

    const f16x8 bH0 = BFRAG(s, tH0);
    const f16x8 bH1 = BFRAG(s, tH0 + 1);
    const f16x8 bH2 = BFRAG(s, tH0 + 2);
    const f16x8 bC0 = BFRAG(s, tC0);
    const f16x8 bC1 = BFRAG(s, tC0 + 1);

    f32x4 gna, gnb;
    const bool pf = (s + 2 < KSTEPS);
    if (pf) {
      gna = *(const f32x4*)(cs + (s - 2) * 32);   // (s+2)-4
      gnb = *(const f32x4*)(cd + (s - 2) * 32);
    }

    FMA2(accH[0][0], a0h, a0l, bH0)
    FMA2(accH[0][1], a1h, a1l, bH0)
    FMA2(accH[1][0], a0h, a0l, bH1)
    FMA2(accH[1][1], a1h, a1l, bH1)
    FMA2(accH[2][0], a0h, a0l, bH2)
    FMA2(accH[2][1], a1h, a1l, bH2)
    FMA2(accC[0][0], a0h, a0l, bC0)
    FMA2(accC[0][1], a1h, a1l, bC0)
    FMA2(accC[1][0], a0h, a0l, bC1)
    FMA2(accC[1][1], a1h, a1l, bC1)

    if (s + 1 < KSTEPS) STAGE(buf ^ 1, gca, gcb)
    __syncthreads();
    if (pf) { gca = gna; gcb = gnb; }
  }

  // retire chemical (valid ? w1 : 0) and combined (valid ? w2 : 0)
#pragma unroll
  for (int t = 0; t < 3; ++t) {
    RETIRE(accH[t][0], tH0 + t, 0, w1c, 0.0f)
    RETIRE(accH[t][1], tH0 + t, 1, w1c, 0.0f)
  }
#pragma unroll
  for (int t = 0; t < 2; ++t) {
    RETIRE(accC[t][0], tC0 + t, 0, w2c, 0.0f)
    RETIRE(accC[t][1], tC0 + t, 1, w2c, 0.0f)
  }

  // ---------------- reduce 16 cols per quad (uniform flow) ---------------
#pragma unroll
  for (int mt = 0; mt < 2; ++mt) {
#pragma unroll
    for (int r = 0; r < 4; ++r) {
      float vv = part[mt][r];
      vv += __shfl_xor(vv, 1);
      vv += __shfl_xor(vv, 2);
      vv += __shfl_xor(vv, 4);
      vv += __shfl_xor(vv, 8);
      part[mt][r] = vv;   // full sum now in every lane
    }
  }
  // per-wave partials to LDS (local 32 rows of this wave's M-group)
  if (li == 0) {
#pragma unroll
    for (int mt = 0; mt < 2; ++mt)
#pragma unroll
      for (int r = 0; r < 4; ++r)
        scoreW[wv][mt * 16 + q * 4 + r] = part[mt][r];
  }
  __syncthreads();

  // final cross-wave sum + bias select: row t served by waves 4*(t>>5)+g
  if (tid < EPB && base + tid < E_EDGES) {
    const int w0 = (tid >> 5) << 2;
    const int lr = tid & 31;
    const float s4 = scoreW[w0][lr] + scoreW[w0 + 1][lr] +
                     scoreW[w0 + 2][lr] + scoreW[w0 + 3][lr];
    const float c3 = consts[3], c4 = consts[4];
    out[base + tid] = s4 + c4 + validL[tid] * (c3 - c4);
  }
}

// ---------------------------------------------------------------------------
extern "C" void kernel_launch(void* const* d_in, const int* in_sizes, int n_in,
                              void* d_out, int out_size, void* d_ws, size_t ws_size,
                              hipStream_t stream)
{
  const float* z    = (const float*)d_in[0];
  const float* chem = (const float*)d_in[1];
  const int*   edge = (const int*)d_in[2];
  const int*   mask = (const int*)d_in[3];
  const float* sw1  = (const float*)d_in[4];
  const float* sb1  = (const float*)d_in[5];
  const float* sw2  = (const float*)d_in[6];
  const float* sb2  = (const float*)d_in[7];
  const float* cw1  = (const float*)d_in[8];
  const float* cb1  = (const float*)d_in[9];
  const float* cw2  = (const float*)d_in[10];
  const float* cb2  = (const float*)d_in[11];
  const float* mw1  = (const float*)d_in[12];
  const float* mb1  = (const float*)d_in[13];
  const float* mw2  = (const float*)d_in[14];
  const float* mb2  = (const float*)d_in[15];
  const float* pw   = (const float*)d_in[16];

  char* ws = (char*)d_ws;
  _Float16* wh  = (_Float16*)(ws + WS_WH);
  float* b1cat  = (float*)(ws + WS_B1);
  float* w2cat  = (float*)(ws + WS_W2);
  float* consts = (float*)(ws + WS_CONST);

  const int prep_tasks  = PTOT + NOUT + 64;
  const int prep_blocks = (prep_tasks + 255) / 256;
  prep_kernel<<<prep_blocks, 256, 0, stream>>>(
      sw1, sb1, sw2, sb2, cw1, cb1, cw2, cb2, mw1, mb1, mw2, mb2, pw, edge,
      wh, b1cat, w2cat, consts);

  decoder_main<<<NBLK, 768, 0, stream>>>(
      z, chem, edge, mask, wh, b1cat, w2cat, consts, (float*)d_out);
}

// Round 4
// 666.231 us; speedup vs baseline: 1.3658x; 1.2332x over previous
//
#include <hip/hip_runtime.h>

// ---------------------------------------------------------------------------
// ChemistryAwareDecoder on MI355X (gfx950)
// N=100000 nodes, E=200000 edges, SD=128, CD=768
// R10: R8/R9 pinned the limiter: L1/TCP line servicing. R6 per block-step =
// 320 B-frag lines + 128 gather lines = 448 ~ 1 cy/line; x3 resident blocks
// matches the 1360cy step wall exactly (MfmaUtil 24%). Cross-wave B sharing
// does NOT help (R9: same lines, slower from barrier coupling). The only
// lever is M-per-B-line WITHIN a wave: this round each wave computes 4
// M-tiles (64 edges/block, 4 waves, disjoint N-groups as in R6). Lines/edge
// 14 -> 9. Occupancy 2 blocks/CU (TCP-bound; R8 proved occupancy isn't it).
// ---------------------------------------------------------------------------

typedef float    f32x4 __attribute__((ext_vector_type(4)));
typedef _Float16 f16x8 __attribute__((ext_vector_type(8)));
typedef _Float16 f16x4 __attribute__((ext_vector_type(4)));

#define E_EDGES 200000
#define EPB     64                    // edges per block
#define NBLK    (E_EDGES / EPB)       // 3125 exactly
#define KSTEPS  28                    // 896 / 32
#define NOUT    384                   // 64 + 192 + 128 fused outputs
#define PTOT    (KSTEPS * NOUT * 32)  // 344064 weight elements
#define PANEL   (NOUT * 32)           // 12288 halfs per k-step panel

// workspace layout (bytes)
#define WS_WH    0
#define WS_B1    688128
#define WS_W2    (688128 + 1536)
#define WS_CONST (688128 + 3072)

// ---------------------------------------------------------------------------
// Prep: fused block-diagonal weight panels in f16 (RNE), fused bias/layer-2
// vectors, softmax consts, edge-dtype detection.
// Panel: wh[p][n][kk], p = k/32, n = 0..383, kk = k%32.
// Wbig[k][n]: n<64: sw1 (k<128) | n<256: cw1 (k>=128) | n>=256: mw1 (all k)
// ---------------------------------------------------------------------------
__global__ __launch_bounds__(256) void prep_kernel(
    const float* __restrict__ sw1, const float* __restrict__ sb1,
    const float* __restrict__ sw2, const float* __restrict__ sb2,
    const float* __restrict__ cw1, const float* __restrict__ cb1,
    const float* __restrict__ cw2, const float* __restrict__ cb2,
    const float* __restrict__ mw1, const float* __restrict__ mb1,
    const float* __restrict__ mw2, const float* __restrict__ mb2,
    const float* __restrict__ pw,  const int* __restrict__ edge_i32,
    _Float16* __restrict__ wh,
    float* __restrict__ b1cat, float* __restrict__ w2cat,
    float* __restrict__ consts)
{
  const int idx = blockIdx.x * 256 + threadIdx.x;
  if (idx < PTOT) {
    const int p  = idx / PANEL;
    const int r  = idx % PANEL;
    const int n  = r >> 5;
    const int kk = r & 31;
    const int k  = p * 32 + kk;
    float v;
    if (n < 64)       v = (k < 128)  ? sw1[k * 64 + n] : 0.0f;
    else if (n < 256) v = (k >= 128) ? cw1[(size_t)(k - 128) * 192 + (n - 64)] : 0.0f;
    else              v = mw1[(size_t)k * 128 + (n - 256)];
    wh[idx] = (_Float16)v;  // RNE
  } else if (idx < PTOT + NOUT) {
    const int j = idx - PTOT;
    float b, w;
    if (j < 64)       { b = sb1[j];       w = sw2[j]; }
    else if (j < 256) { b = cb1[j - 64];  w = cw2[j - 64]; }
    else              { b = mb1[j - 256]; w = mw2[j - 256]; }
    b1cat[j] = b;
    w2cat[j] = w;
  } else if (idx == PTOT + NOUT) {
    const float p0 = pw[0], p1 = pw[1], p2 = pw[2];
    const float mx = fmaxf(p0, fmaxf(p1, p2));
    const float e0 = __expf(p0 - mx), e1 = __expf(p1 - mx), e2 = __expf(p2 - mx);
    const float inv = 1.0f / (e0 + e1 + e2);
    const float w0 = e0 * inv, w1 = e1 * inv, w2v = e2 * inv;
    consts[0] = w0; consts[1] = w1; consts[2] = w2v;
    consts[3] = w0 * sb2[0] + w1 * cb2[0] + w2v * mb2[0];  // valid-path bias
    consts[4] = sb2[0];                                    // invalid-path bias
    unsigned o = 0;
    for (int i = 0; i < 64; ++i) o |= (unsigned)edge_i32[2 * i + 1];
    consts[5] = (o == 0u) ? 1.0f : 0.0f;  // 1 => int64 edge layout
  }
}

// f16x2 compensated: (ah+al)*bh = a*bh; error ~ 2^-12 |ab| per term
#define FMA2(ACC, AH, AL, B)                                              \
  ACC = __builtin_amdgcn_mfma_f32_16x16x32_f16(AH, B, ACC, 0, 0, 0);      \
  ACC = __builtin_amdgcn_mfma_f32_16x16x32_f16(AL, B, ACC, 0, 0, 0);

// ---------------------------------------------------------------------------
// Main: grid = 3125 blocks of 256 threads (4 waves). Block owns edges
// [64b, 64b+64) as 4 M-tiles of 16 rows. N-tiles: 0-3 structural (k<128),
// 4-15 chemical (k>=128), 16-23 combined (all k). Wave g owns N-group g over
// ALL 4 M-tiles: S{g} (phase A), H{4+3g..6+3g} (phase B), C{16+2g,17+2g}
// (both) -> 8 MFMAs per B-fragment load instead of 4 (TCP lines/edge halved
// on the B side). Staging: thread tid covers rows m0=tid>>3 and m1=m0+32 at
// k-chunk (tid&7)*4 (8 consecutive lanes per 128B row segment, lines unique
// per instruction); products split f16 hi/lo into double-buffered LDS.
// 2-step-deep gather prefetch, 1 barrier/step (R6's proven schedule).
// ---------------------------------------------------------------------------
__global__ __launch_bounds__(256, 2) void decoder_main(
    const float* __restrict__ z, const float* __restrict__ chem,
    const int* __restrict__ edge, const int* __restrict__ mask,
    const _Float16* __restrict__ wh,
    const float* __restrict__ b1cat, const float* __restrict__ w2cat,
    const float* __restrict__ consts, float* __restrict__ out)
{
  __shared__ _Float16 Ah[2][64][40];  // stride 40 halfs: 2-way banks, 8B-align
  __shared__ _Float16 Al[2][64][40];
  __shared__ int   srcL[64];
  __shared__ int   dstL[64];
  __shared__ float validL[64];
  __shared__ float scoreW[4][64];

  const int tid  = threadIdx.x;
  const int lane = tid & 63;
  const int g    = tid >> 6;          // wave index = N-group 0..3
  const int li   = lane & 15;
  const int q    = lane >> 4;
  const int q8   = q << 3;
  const int base = blockIdx.x * EPB;  // E = 3125*64 exactly

  if (tid < EPB) {
    const int e = base + tid;
    int s_, d_;
    if (consts[5] > 0.5f) { s_ = edge[4 * e]; d_ = edge[4 * e + 2]; }  // int64
    else                  { s_ = edge[2 * e]; d_ = edge[2 * e + 1]; }  // int32
    srcL[tid] = s_;
    dstL[tid] = d_;
    validL[tid] = (mask[s_] != 0 && mask[d_] != 0) ? 1.0f : 0.0f;
  }
  __syncthreads();

  // cooperative staging: thread covers rows m0 and m1 = m0+32, k-chunk kc.
  // 8 consecutive lanes cover one 128B row segment -> unique lines per instr.
  const int m0 = tid >> 3;            // 0..31
  const int m1 = m0 + 32;             // 32..63
  const int kc = (tid & 7) << 2;
  const float* zs0 = z    + (size_t)srcL[m0] * 128 + kc;
  const float* zd0 = z    + (size_t)dstL[m0] * 128 + kc;
  const float* cs0 = chem + (size_t)srcL[m0] * 768 + kc;
  const float* cd0 = chem + (size_t)dstL[m0] * 768 + kc;
  const float* zs1 = z    + (size_t)srcL[m1] * 128 + kc;
  const float* zd1 = z    + (size_t)dstL[m1] * 128 + kc;
  const float* cs1 = chem + (size_t)srcL[m1] * 768 + kc;
  const float* cd1 = chem + (size_t)dstL[m1] * 768 + kc;

  // gather for k-step t (t<4: z, else chem), both row sets
#define GLOAD(T, A0, B0, A1, B1)                            \
  if ((T) < 4) {                                            \
    A0 = *(const f32x4*)(zs0 + (T) * 32);                   \
    B0 = *(const f32x4*)(zd0 + (T) * 32);                   \
    A1 = *(const f32x4*)(zs1 + (T) * 32);                   \
    B1 = *(const f32x4*)(zd1 + (T) * 32);                   \
  } else {                                                  \
    A0 = *(const f32x4*)(cs0 + ((T) - 4) * 32);             \
    B0 = *(const f32x4*)(cd0 + ((T) - 4) * 32);             \
    A1 = *(const f32x4*)(cs1 + ((T) - 4) * 32);             \
    B1 = *(const f32x4*)(cd1 + ((T) - 4) * 32);             \
  }

  // products -> f16 hi/lo -> LDS for both rows (8B to Ah + 8B to Al each)
#define STAGE(BUF, PA0, PB0, PA1, PB1)                      \
  {                                                         \
    f16x4 h0_, l0_, h1_, l1_;                               \
    _Pragma("unroll")                                       \
    for (int j = 0; j < 4; ++j) {                           \
      const float p0_ = (PA0)[j] * (PB0)[j];                \
      const _Float16 hh0 = (_Float16)p0_;                   \
      h0_[j] = hh0;                                         \
      l0_[j] = (_Float16)(p0_ - (float)hh0);                \
      const float p1_ = (PA1)[j] * (PB1)[j];                \
      const _Float16 hh1 = (_Float16)p1_;                   \
      h1_[j] = hh1;                                         \
      l1_[j] = (_Float16)(p1_ - (float)hh1);                \
    }                                                       \
    *(f16x4*)&Ah[BUF][m0][kc] = h0_;                        \
    *(f16x4*)&Al[BUF][m0][kc] = l0_;                        \
    *(f16x4*)&Ah[BUF][m1][kc] = h1_;                        \
    *(f16x4*)&Al[BUF][m1][kc] = l1_;                        \
  }

  // B fragment: tile ti at step s (proven panel indexing)
#define BFRAG(S, TI) \
  (*(const f16x8*)(wh + (size_t)(S) * PANEL + ((TI) * 16 + li) * 32 + q8))

  // A fragments: 4 M-tiles from LDS buffer
#define AFRAGS(BUF)                                         \
  f16x8 a0h = *(const f16x8*)&Ah[BUF][li][q8];              \
  f16x8 a0l = *(const f16x8*)&Al[BUF][li][q8];              \
  f16x8 a1h = *(const f16x8*)&Ah[BUF][16 + li][q8];         \
  f16x8 a1l = *(const f16x8*)&Al[BUF][16 + li][q8];         \
  f16x8 a2h = *(const f16x8*)&Ah[BUF][32 + li][q8];         \
  f16x8 a2l = *(const f16x8*)&Al[BUF][32 + li][q8];         \
  f16x8 a3h = *(const f16x8*)&Ah[BUF][48 + li][q8];         \
  f16x8 a3l = *(const f16x8*)&Al[BUF][48 + li][q8];

  // apply one B-fragment to all 4 M-tile accumulators (8 MFMAs per B load)
#define FMA2x4(ACCARR, B)                                   \
  FMA2(ACCARR[0], a0h, a0l, B)                              \
  FMA2(ACCARR[1], a1h, a1l, B)                              \
  FMA2(ACCARR[2], a2h, a2l, B)                              \
  FMA2(ACCARR[3], a3h, a3l, B)

  const float w0c = consts[0], w1c = consts[1], w2c = consts[2];

  float part[4][4];
#pragma unroll
  for (int mt = 0; mt < 4; ++mt)
#pragma unroll
    for (int r = 0; r < 4; ++r) part[mt][r] = 0.0f;

  // retire one tile's acc into part with path weighting.
  // C/D layout: col = ti*16+li, row = mt*16 + q*4+r.
#define RETIRE(ACC, TI, MT, WVALID, WINVALID)                              \
  {                                                                        \
    const int col = (TI) * 16 + li;                                        \
    const float b1 = b1cat[col];                                           \
    const float w2 = w2cat[col];                                           \
    _Pragma("unroll")                                                      \
    for (int r = 0; r < 4; ++r) {                                          \
      const float vld = validL[(MT) * 16 + q * 4 + r];                     \
      const float a = (WINVALID) + vld * ((WVALID) - (WINVALID));          \
      part[MT][r] += a * fmaxf((ACC)[r] + b1, 0.0f) * w2;                  \
    }                                                                      \
  }

  // this wave's tile indices
  const int tS  = g;              // structural, phase A
  const int tH0 = 4 + 3 * g;      // chemical, phase B
  const int tC0 = 16 + 2 * g;     // combined, both phases

  // ---- pipeline prologue: stage s=0; prefetch s=1 --------------------
  {
    f32x4 a0, b0, a1, b1;
    GLOAD(0, a0, b0, a1, b1)
    STAGE(0, a0, b0, a1, b1)
  }
  f32x4 gca0, gcb0, gca1, gcb1;   // gathers for step s+1 (consumed next STAGE)
  GLOAD(1, gca0, gcb0, gca1, gcb1)
  __syncthreads();

  // ---------------- phase A: s = 0..3 (S + C tiles) ----------------------
  f32x4 accS[4], accC[2][4];
#pragma unroll
  for (int mt = 0; mt < 4; ++mt) {
    accS[mt]    = (f32x4){0.f, 0.f, 0.f, 0.f};
    accC[0][mt] = (f32x4){0.f, 0.f, 0.f, 0.f};
    accC[1][mt] = (f32x4){0.f, 0.f, 0.f, 0.f};
  }

#pragma unroll
  for (int s = 0; s < 4; ++s) {
    const int buf = s & 1;
    AFRAGS(buf)

    const f16x8 bS  = BFRAG(s, tS);
    const f16x8 bC0 = BFRAG(s, tC0);
    const f16x8 bC1 = BFRAG(s, tC0 + 1);

    // prefetch s+2 (two full steps to land)
    f32x4 gna0, gnb0, gna1, gnb1;
    GLOAD(s + 2, gna0, gnb0, gna1, gnb1)

    FMA2x4(accS,    bS)
    FMA2x4(accC[0], bC0)
    FMA2x4(accC[1], bC1)

    STAGE(buf ^ 1, gca0, gcb0, gca1, gcb1)   // stage s+1 from older prefetch
    __syncthreads();
    gca0 = gna0; gcb0 = gnb0; gca1 = gna1; gcb1 = gnb1;
  }

  // retire structural (k-range done): valid ? w0 : 1
#pragma unroll
  for (int mt = 0; mt < 4; ++mt) {
    RETIRE(accS[mt], tS, mt, w0c, 1.0f)
  }

  // ---------------- phase B: s = 4..27 (H + C tiles) ----------------------
  f32x4 accH[3][4];
#pragma unroll
  for (int t = 0; t < 3; ++t)
#pragma unroll
    for (int mt = 0; mt < 4; ++mt)
      accH[t][mt] = (f32x4){0.f, 0.f, 0.f, 0.f};

  for (int s = 4; s < KSTEPS; ++s) {
    const int buf = s & 1;
    AFRAGS(buf)

    const f16x8 bH0 = BFRAG(s, tH0);
    const f16x8 bH1 = BFRAG(s, tH0 + 1);
    const f16x8 bH2 = BFRAG(s, tH0 + 2);
    const f16x8 bC0 = BFRAG(s, tC0);
    const f16x8 bC1 = BFRAG(s, tC0 + 1);

    f32x4 gna0, gnb0, gna1, gnb1;
    const bool pf = (s + 2 < KSTEPS);
    if (pf) {
      gna0 = *(const f32x4*)(cs0 + (s - 2) * 32);   // (s+2)-4
      gnb0 = *(const f32x4*)(cd0 + (s - 2) * 32);
      gna1 = *(const f32x4*)(cs1 + (s - 2) * 32);
      gnb1 = *(const f32x4*)(cd1 + (s - 2) * 32);
    }

    FMA2x4(accH[0], bH0)
    FMA2x4(accH[1], bH1)
    FMA2x4(accH[2], bH2)
    FMA2x4(accC[0], bC0)
    FMA2x4(accC[1], bC1)

    if (s + 1 < KSTEPS) STAGE(buf ^ 1, gca0, gcb0, gca1, gcb1)
    __syncthreads();
    if (pf) { gca0 = gna0; gcb0 = gnb0; gca1 = gna1; gcb1 = gnb1; }
  }

  // retire chemical (valid ? w1 : 0) and combined (valid ? w2 : 0)
#pragma unroll
  for (int t = 0; t < 3; ++t)
#pragma unroll
    for (int mt = 0; mt < 4; ++mt) {
      RETIRE(accH[t][mt], tH0 + t, mt, w1c, 0.0f)
    }
#pragma unroll
  for (int t = 0; t < 2; ++t)
#pragma unroll
    for (int mt = 0; mt < 4; ++mt) {
      RETIRE(accC[t][mt], tC0 + t, mt, w2c, 0.0f)
    }

  // ---------------- reduce 16 cols per quad (uniform flow) ---------------
#pragma unroll
  for (int mt = 0; mt < 4; ++mt) {
#pragma unroll
    for (int r = 0; r < 4; ++r) {
      float vv = part[mt][r];
      vv += __shfl_xor(vv, 1);
      vv += __shfl_xor(vv, 2);
      vv += __shfl_xor(vv, 4);
      vv += __shfl_xor(vv, 8);
      part[mt][r] = vv;   // full sum now in every lane
    }
  }
  // per-wave partials to LDS (this wave covers all 64 rows, 16 cols)
  if (li == 0) {
#pragma unroll
    for (int mt = 0; mt < 4; ++mt)
#pragma unroll
      for (int r = 0; r < 4; ++r)
        scoreW[g][mt * 16 + q * 4 + r] = part[mt][r];
  }
  __syncthreads();

  // final cross-wave (cross-N-group) sum + bias select
  if (tid < EPB) {
    const float s4 = scoreW[0][tid] + scoreW[1][tid] + scoreW[2][tid] + scoreW[3][tid];
    const float c3 = consts[3], c4 = consts[4];
    out[base + tid] = s4 + c4 + validL[tid] * (c3 - c4);
  }
}

// ---------------------------------------------------------------------------
extern "C" void kernel_launch(void* const* d_in, const int* in_sizes, int n_in,
                              void* d_out, int out_size, void* d_ws, size_t ws_size,
                              hipStream_t stream)
{
  const float* z    = (const float*)d_in[0];
  const float* chem = (const float*)d_in[1];
  const int*   edge = (const int*)d_in[2];
  const int*   mask = (const int*)d_in[3];
  const float* sw1  = (const float*)d_in[4];
  const float* sb1  = (const float*)d_in[5];
  const float* sw2  = (const float*)d_in[6];
  const float* sb2  = (const float*)d_in[7];
  const float* cw1  = (const float*)d_in[8];
  const float* cb1  = (const float*)d_in[9];
  const float* cw2  = (const float*)d_in[10];
  const float* cb2  = (const float*)d_in[11];
  const float* mw1  = (const float*)d_in[12];
  const float* mb1  = (const float*)d_in[13];
  const float* mw2  = (const float*)d_in[14];
  const float* mb2  = (const float*)d_in[15];
  const float* pw   = (const float*)d_in[16];

  char* ws = (char*)d_ws;
  _Float16* wh  = (_Float16*)(ws + WS_WH);
  float* b1cat  = (float*)(ws + WS_B1);
  float* w2cat  = (float*)(ws + WS_W2);
  float* consts = (float*)(ws + WS_CONST);

  const int prep_tasks  = PTOT + NOUT + 64;
  const int prep_blocks = (prep_tasks + 255) / 256;
  prep_kernel<<<prep_blocks, 256, 0, stream>>>(
      sw1, sb1, sw2, sb2, cw1, cb1, cw2, cb2, mw1, mb1, mw2, mb2, pw, edge,
      wh, b1cat, w2cat, consts);

  decoder_main<<<NBLK, 256, 0, stream>>>(
      z, chem, edge, mask, wh, b1cat, w2cat, consts, (float*)d_out);
}